// Round 1
// baseline (170.787 us; speedup 1.0000x reference)
//
#include <hip/hip_runtime.h>
#include <hip/hip_bf16.h>

// FlatConv3x3NNUE: 25 per-position conv towers (2x2,2x2,1x1,1x1) + clip-sum + NNUE head.
// Plan: prep (weights -> bf16 MFMA-fragment layout in ws) -> tower (MFMA, 16 rows/wave,
// 5 position-groups, partial features to ws) -> head (reduce + MLP).

#define NPOS 25
#define BATCH 8192
#define CMAXF 0.9921875f
#define NGRP 5
#define PPG 5

// ws layout in bf16 elements
#define W1F_OFF 0           // [25][32][64][8]   (K=18->32 padded, N=512 = 4 spatial x 128)
#define W2F_OFF 409600      // [25][8][16][64][8] (K=512, N=128)
#define W3F_OFF 2048000     // [25][8][4][64][8]  (K=128, N=128)
#define W4F_OFF 2457600     // [25][2][4][64][8]  (K=128, N=32)
#define WF_TOTAL 2560000
#define PART_BYTE_OFF 5120000  // float [5][8192][32] partial features

using bf16x8 = __attribute__((ext_vector_type(8))) short;
using f32x4  = __attribute__((ext_vector_type(4))) float;

__device__ __forceinline__ unsigned short f2bf(float f) {
  union { float f; unsigned u; } v; v.f = f;
  unsigned u = v.u + 0x7fffu + ((v.u >> 16) & 1u);   // RNE
  return (unsigned short)(u >> 16);
}

__device__ __forceinline__ f32x4 mfma16(bf16x8 a, bf16x8 b, f32x4 c) {
  return __builtin_amdgcn_mfma_f32_16x16x32_bf16(a, b, c, 0, 0, 0);
}

// ---------------- prep: weights -> bf16 fragment-linear ----------------
__global__ __launch_bounds__(256) void prep_kernel(
    const float* __restrict__ W1, const float* __restrict__ W2,
    const float* __restrict__ W3, const float* __restrict__ W4,
    unsigned short* __restrict__ wf)
{
  int idx = blockIdx.x * 256 + threadIdx.x;
  if (idx >= WF_TOTAL) return;
  float val = 0.f;
  if (idx < W2F_OFF) {              // W1e: K=18 (c*9+py*3+px), padded to 32; N=512 (s*128+o)
    int e = idx; int j = e & 7; int l = (e >> 3) & 63; int nt = (e >> 9) & 31; int p = e >> 14;
    int k = (l >> 4) * 8 + j;
    int n = nt * 16 + (l & 15);
    int s = n >> 7, o = n & 127;
    int si = s >> 1, sj = s & 1;
    if (k < 18) {
      int c = (k >= 9) ? 1 : 0;
      int rr = k - c * 9;
      int py = rr / 3, px = rr - (rr / 3) * 3;
      int di = py - si, dj = px - sj;
      if (di >= 0 && di < 2 && dj >= 0 && dj < 2)
        val = W1[((p * 128 + o) * 2 + c) * 4 + di * 2 + dj];
    }
  } else if (idx < W3F_OFF) {       // W2: k2 = s*128 + c
    int e = idx - W2F_OFF; int j = e & 7; int l = (e >> 3) & 63;
    int kq = (e >> 9) & 15; int nt = (e >> 13) & 7; int p = e >> 16;
    int k2 = kq * 32 + (l >> 4) * 8 + j;
    int o = nt * 16 + (l & 15);
    int s = k2 >> 7, c = k2 & 127;
    val = W2[((p * 128 + o) * 128 + c) * 4 + s];
  } else if (idx < W4F_OFF) {       // W3[o][c]
    int e = idx - W3F_OFF; int j = e & 7; int l = (e >> 3) & 63;
    int kq = (e >> 9) & 3; int nt = (e >> 11) & 7; int p = e >> 14;
    int k = kq * 32 + (l >> 4) * 8 + j;
    int o = nt * 16 + (l & 15);
    val = W3[(p * 128 + o) * 128 + k];
  } else {                          // W4[o][c]
    int e = idx - W4F_OFF; int j = e & 7; int l = (e >> 3) & 63;
    int kq = (e >> 9) & 3; int nt = (e >> 11) & 1; int p = e >> 12;
    int k = kq * 32 + (l >> 4) * 8 + j;
    int o = nt * 16 + (l & 15);
    val = W4[(p * 32 + o) * 128 + k];
  }
  wf[idx] = f2bf(val);
}

// ---------------- tower: MFMA pipeline, 1 wave / 16 rows / 5 positions ----------------
__global__ __launch_bounds__(64, 2) void tower_kernel(
    const float* __restrict__ x,
    const float* __restrict__ b1v, const float* __restrict__ b2v,
    const float* __restrict__ b3v, const float* __restrict__ b4v,
    const unsigned short* __restrict__ wf, float* __restrict__ part)
{
  __shared__ __align__(16) unsigned short xs[16 * 104];   // [row][c*52+pix]
  __shared__ __align__(16) unsigned short hsb[16 * 128];  // L1 out (per spatial), swizzled
  __shared__ __align__(16) unsigned short h2b[16 * 128];
  __shared__ __align__(16) unsigned short h3b[16 * 128];

  const int l = threadIdx.x;
  const int l15 = l & 15;
  const int g = l >> 4;

  // XCD-aware remap so each XCD sees mostly 1-2 position groups (weights stay L2-resident)
  int bid = blockIdx.x;
  int lin = (bid & 7) * 320 + (bid >> 3);
  int grp = lin / 512;
  int btile = lin - grp * 512;
  const int R0 = btile * 16;

  for (int idx = l; idx < 16 * 98; idx += 64) {
    int r = idx / 98;
    int q = idx - r * 98;
    int c = q / 49;
    int pix = q - c * 49;
    xs[r * 104 + c * 52 + pix] = f2bf(x[(R0 + r) * 98 + q]);
  }
  __syncthreads();

  // per-lane K-slot decode for the L1 fragment (fixed per lane)
  int kbase[8]; bool kreal[8];
#pragma unroll
  for (int j = 0; j < 8; ++j) {
    int k = g * 8 + j;
    if (k < 18) {
      int c = (k >= 9) ? 1 : 0;
      int rr = k - c * 9;
      int py = rr / 3, px = rr - (rr / 3) * 3;
      kbase[j] = c * 52 + py * 7 + px;
      kreal[j] = true;
    } else { kbase[j] = 0; kreal[j] = false; }
  }

  const f32x4 zf = {0.f, 0.f, 0.f, 0.f};
  f32x4 facc0 = zf, facc1 = zf;

  for (int pp = 0; pp < PPG; ++pp) {
    const int p = grp * PPG + pp;
    const int y0 = p / 5;
    const int x0 = p - y0 * 5;
    const int poff = y0 * 7 + x0;

    bf16x8 a1;
#pragma unroll
    for (int j = 0; j < 8; ++j) {
      unsigned short v = kreal[j] ? xs[l15 * 104 + kbase[j] + poff] : (unsigned short)0;
      a1[j] = (short)v;
    }

    float bias1[8];
#pragma unroll
    for (int t = 0; t < 8; ++t) bias1[t] = b1v[p * 128 + t * 16 + l15];

    f32x4 acc2[8];
#pragma unroll
    for (int t = 0; t < 8; ++t) acc2[t] = zf;

    const unsigned short* w1p = wf + W1F_OFF + (p * 32) * 512 + l * 8;
    const unsigned short* w2p = wf + W2F_OFF + (p * 8) * 16 * 512 + l * 8;

    for (int s = 0; s < 4; ++s) {
      // L1 (this spatial): 8 n-tiles, K=32 (18 real)
#pragma unroll
      for (int t = 0; t < 8; ++t) {
        bf16x8 bw = *(const bf16x8*)(w1p + (s * 8 + t) * 512);
        f32x4 c1 = mfma16(a1, bw, zf);
#pragma unroll
        for (int r = 0; r < 4; ++r) {
          int row = g * 4 + r;
          float v = c1[r] + bias1[t];
          v = v > 0.f ? v : 0.f;
          hsb[(row * 128 + (t * 16 + l15)) ^ ((row & 7) << 3)] = f2bf(v);
        }
      }
      __syncthreads();
      // L2 partial over this spatial's 128 input channels
#pragma unroll
      for (int kq = 0; kq < 4; ++kq) {
        bf16x8 a2 = *(const bf16x8*)&hsb[(l15 * 128 + (kq * 32 + g * 8)) ^ ((l15 & 7) << 3)];
#pragma unroll
        for (int t = 0; t < 8; ++t) {
          bf16x8 bw = *(const bf16x8*)(w2p + (t * 16 + (s * 4 + kq)) * 512);
          acc2[t] = mfma16(a2, bw, acc2[t]);
        }
      }
      __syncthreads();
    }

    // L2 epilogue -> h2
#pragma unroll
    for (int t = 0; t < 8; ++t) {
      float bias = b2v[p * 128 + t * 16 + l15];
#pragma unroll
      for (int r = 0; r < 4; ++r) {
        int row = g * 4 + r;
        float v = acc2[t][r] + bias;
        v = v > 0.f ? v : 0.f;
        h2b[(row * 128 + (t * 16 + l15)) ^ ((row & 7) << 3)] = f2bf(v);
      }
    }
    __syncthreads();

    // L3
    f32x4 acc3[8];
#pragma unroll
    for (int t = 0; t < 8; ++t) acc3[t] = zf;
    const unsigned short* w3p = wf + W3F_OFF + (p * 8) * 4 * 512 + l * 8;
#pragma unroll
    for (int kq = 0; kq < 4; ++kq) {
      bf16x8 a = *(const bf16x8*)&h2b[(l15 * 128 + (kq * 32 + g * 8)) ^ ((l15 & 7) << 3)];
#pragma unroll
      for (int t = 0; t < 8; ++t) {
        bf16x8 bw = *(const bf16x8*)(w3p + (t * 4 + kq) * 512);
        acc3[t] = mfma16(a, bw, acc3[t]);
      }
    }
#pragma unroll
    for (int t = 0; t < 8; ++t) {
      float bias = b3v[p * 128 + t * 16 + l15];
#pragma unroll
      for (int r = 0; r < 4; ++r) {
        int row = g * 4 + r;
        float v = acc3[t][r] + bias;
        v = v > 0.f ? v : 0.f;
        h3b[(row * 128 + (t * 16 + l15)) ^ ((row & 7) << 3)] = f2bf(v);
      }
    }
    __syncthreads();

    // L4 + clamp + accumulate feature (fp32, in regs)
    f32x4 c40 = zf, c41 = zf;
    const unsigned short* w4p = wf + W4F_OFF + (p * 2) * 4 * 512 + l * 8;
#pragma unroll
    for (int kq = 0; kq < 4; ++kq) {
      bf16x8 a = *(const bf16x8*)&h3b[(l15 * 128 + (kq * 32 + g * 8)) ^ ((l15 & 7) << 3)];
      bf16x8 bw0 = *(const bf16x8*)(w4p + (0 * 4 + kq) * 512);
      bf16x8 bw1 = *(const bf16x8*)(w4p + (1 * 4 + kq) * 512);
      c40 = mfma16(a, bw0, c40);
      c41 = mfma16(a, bw1, c41);
    }
    __syncthreads();
    {
      float bias0 = b4v[p * 32 + l15];
      float bias1b = b4v[p * 32 + 16 + l15];
#pragma unroll
      for (int r = 0; r < 4; ++r) {
        float v0 = c40[r] + bias0;
        v0 = v0 < -1.f ? -1.f : (v0 > CMAXF ? CMAXF : v0);
        facc0[r] += v0;
        float v1 = c41[r] + bias1b;
        v1 = v1 < -1.f ? -1.f : (v1 > CMAXF ? CMAXF : v1);
        facc1[r] += v1;
      }
    }
  }

#pragma unroll
  for (int r = 0; r < 4; ++r) {
    int row = R0 + g * 4 + r;
    part[(grp * BATCH + row) * 32 + l15] = facc0[r];
    part[(grp * BATCH + row) * 32 + 16 + l15] = facc1[r];
  }
}

// ---------------- head: reduce partials + clipped MLP ----------------
__global__ __launch_bounds__(256) void head_kernel(
    const float* __restrict__ part,
    const float* __restrict__ fc1w, const float* __restrict__ fc1b,
    const float* __restrict__ fc2w, const float* __restrict__ fc2b,
    const float* __restrict__ fc3w, const float* __restrict__ fc3b,
    float* __restrict__ out)
{
  int r = blockIdx.x * 256 + threadIdx.x;
  float feat[32];
#pragma unroll
  for (int i = 0; i < 32; ++i) feat[i] = 0.f;
#pragma unroll
  for (int gi = 0; gi < NGRP; ++gi) {
    const float4* pr = (const float4*)(part + ((size_t)gi * BATCH + r) * 32);
#pragma unroll
    for (int q = 0; q < 8; ++q) {
      float4 v = pr[q];
      feat[q * 4 + 0] += v.x; feat[q * 4 + 1] += v.y;
      feat[q * 4 + 2] += v.z; feat[q * 4 + 3] += v.w;
    }
  }
#pragma unroll
  for (int i = 0; i < 32; ++i) {
    float v = feat[i];
    feat[i] = v < 0.f ? 0.f : (v > CMAXF ? CMAXF : v);
  }
  float v1[32];
  for (int o = 0; o < 32; ++o) {
    float a = fc1b[o];
    for (int k = 0; k < 32; ++k) a += feat[k] * fc1w[o * 32 + k];
    v1[o] = a < 0.f ? 0.f : (a > CMAXF ? CMAXF : a);
  }
  float v2[32];
  for (int o = 0; o < 32; ++o) {
    float a = fc2b[o];
    for (int k = 0; k < 32; ++k) a += v1[k] * fc2w[o * 32 + k];
    v2[o] = a < 0.f ? 0.f : (a > CMAXF ? CMAXF : a);
  }
  float a = fc3b[0];
  for (int k = 0; k < 32; ++k) a += v2[k] * fc3w[k];
  out[r] = a;
}

extern "C" void kernel_launch(void* const* d_in, const int* in_sizes, int n_in,
                              void* d_out, int out_size, void* d_ws, size_t ws_size,
                              hipStream_t stream) {
  const float* x    = (const float*)d_in[0];
  const float* W1   = (const float*)d_in[1];
  const float* b1   = (const float*)d_in[2];
  const float* W2   = (const float*)d_in[3];
  const float* b2   = (const float*)d_in[4];
  const float* W3   = (const float*)d_in[5];
  const float* b3   = (const float*)d_in[6];
  const float* W4   = (const float*)d_in[7];
  const float* b4   = (const float*)d_in[8];
  const float* fc1w = (const float*)d_in[9];
  const float* fc1b = (const float*)d_in[10];
  const float* fc2w = (const float*)d_in[11];
  const float* fc2b = (const float*)d_in[12];
  const float* fc3w = (const float*)d_in[13];
  const float* fc3b = (const float*)d_in[14];
  float* out = (float*)d_out;

  unsigned short* wf = (unsigned short*)d_ws;
  float* part = (float*)((char*)d_ws + PART_BYTE_OFF);

  prep_kernel<<<(WF_TOTAL + 255) / 256, 256, 0, stream>>>(W1, W2, W3, W4, wf);
  tower_kernel<<<2560, 64, 0, stream>>>(x, b1, b2, b3, b4, wf, part);
  head_kernel<<<BATCH / 256, 256, 0, stream>>>(part, fc1w, fc1b, fc2w, fc2b, fc3w, fc3b, out);
}